// Round 14
// baseline (128.127 us; speedup 1.0000x reference)
//
#include <hip/hip_runtime.h>

#define DIM 256
#define NA 16
#define NE 4
#define KTOT 288   // 16 atoms + 256 latent + 16 zero pad

typedef __attribute__((ext_vector_type(8))) short short8;
typedef __attribute__((ext_vector_type(4))) float f32x4;

static __device__ __forceinline__ ushort f2bf(float f) {
  union { float f; unsigned int u; } v; v.f = f;
  unsigned int r = (v.u + 0x7FFFu + ((v.u >> 16) & 1u)) >> 16;
  return (ushort)r;
}

static __device__ __forceinline__ float bf2f(ushort s) {
  union { unsigned int u; float f; } v; v.u = ((unsigned int)s) << 16;
  return v.f;
}

static __device__ __forceinline__ unsigned cvtpk(float lo, float hi) {
  unsigned r;
  asm("v_cvt_pk_bf16_f32 %0, %1, %2" : "=v"(r) : "v"(lo), "v"(hi));
  return r;
}

// async global->LDS DMA, 16B per lane; lds dest wave-uniform (HW adds lane*16)
static __device__ __forceinline__ void gll16(const void* g, void* l) {
  __builtin_amdgcn_global_load_lds((const __attribute__((address_space(1))) void*)g,
                                   (__attribute__((address_space(3))) void*)l, 16, 0, 0);
}

// ---------------- prep 1: h = relu(latent@W1+b1)@W2+b2 ; build G = [atoms|h|0] bf16
__global__ __launch_bounds__(256) void prep_h_kernel(
    const float* __restrict__ latent, const float* __restrict__ atoms,
    const float* __restrict__ W1, const float* __restrict__ b1,
    const float* __restrict__ W2, const float* __restrict__ b2,
    float* __restrict__ h_out, ushort* __restrict__ G_out) {
  __shared__ float lat[8][DIM];
  __shared__ float t1[8][DIM];
  const int b = blockIdx.x >> 5, i0 = (blockIdx.x & 31) * 8;
  const int k = threadIdx.x;
  #pragma unroll
  for (int r = 0; r < 8; ++r) lat[r][k] = latent[(b*256 + i0 + r) * DIM + k];
  __syncthreads();
  float acc[8];
  #pragma unroll
  for (int r = 0; r < 8; ++r) acc[r] = b1[k];
  for (int c = 0; c < DIM; c += 4) {
    float w0 = W1[(c+0)*DIM + k], w1 = W1[(c+1)*DIM + k];
    float w2 = W1[(c+2)*DIM + k], w3 = W1[(c+3)*DIM + k];
    #pragma unroll
    for (int r = 0; r < 8; ++r) {
      const float4 l4 = *reinterpret_cast<const float4*>(&lat[r][c]);
      acc[r] += l4.x*w0 + l4.y*w1 + l4.z*w2 + l4.w*w3;
    }
  }
  #pragma unroll
  for (int r = 0; r < 8; ++r) t1[r][k] = fmaxf(acc[r], 0.f);
  __syncthreads();
  #pragma unroll
  for (int r = 0; r < 8; ++r) acc[r] = b2[k];
  for (int c = 0; c < DIM; c += 4) {
    float w0 = W2[(c+0)*DIM + k], w1 = W2[(c+1)*DIM + k];
    float w2 = W2[(c+2)*DIM + k], w3 = W2[(c+3)*DIM + k];
    #pragma unroll
    for (int r = 0; r < 8; ++r) {
      const float4 l4 = *reinterpret_cast<const float4*>(&t1[r][c]);
      acc[r] += l4.x*w0 + l4.y*w1 + l4.z*w2 + l4.w*w3;
    }
  }
  #pragma unroll
  for (int r = 0; r < 8; ++r) {
    int row = b*256 + i0 + r;
    h_out[row*DIM + k] = acc[r];
    G_out[row*KTOT + NA + k] = f2bf(acc[r]);
  }
  if (k < NA) {
    #pragma unroll
    for (int r = 0; r < 8; ++r) {
      int row = b*256 + i0 + r;
      G_out[row*KTOT + k] = f2bf(atoms[row*NA + k]);
      G_out[row*KTOT + 272 + k] = 0;
    }
  }
}

// ---------------- prep 2: W3T[n][c] = bf16(W3[1+c][n]) zero-padded to 288
__global__ __launch_bounds__(256) void prep_w3t_kernel(
    const float* __restrict__ W3, ushort* __restrict__ W3T) {
  const int kk = blockIdx.x, c = threadIdx.x;
  W3T[kk*KTOT + c] = (c < 272) ? f2bf(W3[(1+c)*DIM + kk]) : (ushort)0;
  if (c < 32) {
    int c2 = 256 + c;
    W3T[kk*KTOT + c2] = (c2 < 272) ? f2bf(W3[(1+c2)*DIM + kk]) : (ushort)0;
  }
}

// ---------------- main: one WG per (b, it<=jt) pair-tile (8*136 = 1088 WGs).
// Dense 256-pair x 256-n x K288 MFMA tile per WG, K split 4x64 + 1x32:
//   A = W3T (rows=n, raw DMA), B = y[pair][c] = G[i][c]*G[j][c] (built in regs).
// Fewer, heavier chunks: 6 barriers total instead of 10 (phase-latency-bound).
__global__ __attribute__((amdgpu_flat_work_group_size(512,512), amdgpu_waves_per_eu(2,2)))
void edge_main_kernel(
    const float* __restrict__ positions,
    const float* __restrict__ W3, const float* __restrict__ b3,
    const float* __restrict__ W4, const float* __restrict__ b4,
    const ushort* __restrict__ G, const ushort* __restrict__ W3T,
    float* __restrict__ out) {
  __shared__ union UU {
    char w3t[2][32768];           // A-operand chunk dbuf (16 ntiles x 2KB)
    float partial[4][256][4];     // epilogue partials (16KB), after final barrier
  } u;
  __shared__ char y_lds[2][32768];   // B-operand chunk dbuf (16 ptiles x 2KB)
  __shared__ float dist_lds[256];

  const int bid = blockIdx.x;
  const int b = bid / 136;
  int q = bid - b*136;
  int it = 0;
  while (q >= 16 - it) { q -= 16 - it; ++it; }
  const int jt = it + q;
  const int i0 = b*256 + it*16, j0 = b*256 + jt*16;   // global row bases

  const int tid = threadIdx.x;
  const int lane = tid & 63, w = tid >> 6;
  const int wn = w & 3;      // n-group: ntiles wn*4 .. +4
  const int wp = w >> 2;     // pair-group: pairs wp*128 .. +128
  const int c15 = lane & 15, hi = lane >> 4;

  // ---- prologue: dist for all 256 pairs of this tile
  if (tid < 256) {
    int pi = tid >> 4, pj = tid & 15;
    const float* pa = &positions[(i0 + pi)*3];
    const float* pb = &positions[(j0 + pj)*3];
    float dx = pa[0]-pb[0], dy = pa[1]-pb[1], dz = pa[2]-pb[2];
    float d2 = dx*dx + dy*dy + dz*dz;
    dist_lds[tid] = d2 > 0.f ? sqrtf(d2) : 0.f;
  }

  // ---- stage W3T chunk kk: big (64c) = 128 subtiles; tail (32c) = 64 subtiles
  auto stage = [&](int kk) {
    const bool big = (kk < 4);
    const int octs = big ? 8 : 4;            // octets per ntile this chunk
    const int nq = big ? 4 : 2;
    for (int qq = 0; qq < nq; ++qq) {
      int s0 = w*(octs*2) + qq*4;            // wave-uniform base subtile
      int sub = s0 + hi;
      int nt_ = sub / octs, oct = sub - nt_*octs;
      const ushort* src = &W3T[(size_t)(nt_*16 + c15)*KTOT + kk*64 + oct*8];
      gll16(src, u.w3t[kk & 1] + s0*256);    // + lane*16 implicit
    }
  };

  // ---- y-build: thread owns (pair = tid>>1, half po = tid&1); 32 cols each
  const int pair_ = tid >> 1, po = tid & 1;
  const int pi_ = pair_ >> 4, pj_ = pair_ & 15;
  const ushort* giRow = &G[(size_t)(i0 + pi_)*KTOT];
  const ushort* gjRow = &G[(size_t)(j0 + pj_)*KTOT];

  short8 yi[4], yj[4];
  auto y_load = [&](int kk) {               // issue early; 32 cols = 4 short8/side
    const bool big = (kk < 4);
    if (big || po == 0) {
      int cb = kk*64 + (big ? po*32 : 0);
      #pragma unroll
      for (int s = 0; s < 4; ++s) {
        yi[s] = *reinterpret_cast<const short8*>(giRow + cb + s*8);
        yj[s] = *reinterpret_cast<const short8*>(gjRow + cb + s*8);
      }
    }
  };
  auto y_finish = [&](int kk) {             // mul + pack + 4x ds_write_b128
    const bool big = (kk < 4);
    if (big || po == 0) {
      char* dst = y_lds[kk & 1] + (big ? (pi_*2048 + po*1024) : pi_*1024) + pj_*16;
      #pragma unroll
      for (int s = 0; s < 4; ++s) {
        union { ushort us[8]; short8 s8; } A, B;
        A.s8 = yi[s]; B.s8 = yj[s];
        uint4 p;
        p.x = cvtpk(bf2f(A.us[0])*bf2f(B.us[0]), bf2f(A.us[1])*bf2f(B.us[1]));
        p.y = cvtpk(bf2f(A.us[2])*bf2f(B.us[2]), bf2f(A.us[3])*bf2f(B.us[3]));
        p.z = cvtpk(bf2f(A.us[4])*bf2f(B.us[4]), bf2f(A.us[5])*bf2f(B.us[5]));
        p.w = cvtpk(bf2f(A.us[6])*bf2f(B.us[6]), bf2f(A.us[7])*bf2f(B.us[7]));
        *reinterpret_cast<uint4*>(dst + s*256) = p;
      }
    }
  };

  f32x4 acc[4][8];
  #pragma unroll
  for (int at = 0; at < 4; ++at)
    #pragma unroll
    for (int bt = 0; bt < 8; ++bt) { acc[at][bt].x=0.f; acc[at][bt].y=0.f; acc[at][bt].z=0.f; acc[at][bt].w=0.f; }

  stage(0);
  y_load(0);
  y_finish(0);
  __syncthreads();   // stage(0) DMA drained; y(0) + dist visible

  #pragma unroll
  for (int kk = 0; kk < 5; ++kk) {
    if (kk < 4) { y_load(kk + 1); stage(kk + 1); }     // into opposite buffers
    // ---- MFMA chunk kk: per 32-col step: 4 A-frags + 8 B-frags, 32 MFMA
    {
      const bool big = (kk < 4);
      const int nts = big ? 2048 : 1024;    // ntile/ptile stride this chunk
      const char* ap = u.w3t[kk & 1];
      const char* bp = y_lds[kk & 1];
      #pragma unroll
      for (int ks = 0; ks < 2; ++ks) {
        if (ks == 0 || big) {
          short8 afr[4];
          #pragma unroll
          for (int at = 0; at < 4; ++at)
            afr[at] = *reinterpret_cast<const short8*>(
                ap + (wn*4 + at)*nts + (ks*4 + hi)*256 + c15*16);
          #pragma unroll
          for (int bt = 0; bt < 8; ++bt) {
            short8 bb = *reinterpret_cast<const short8*>(
                bp + (wp*8 + bt)*nts + (ks*4 + hi)*256 + c15*16);
            acc[0][bt] = __builtin_amdgcn_mfma_f32_16x16x32_bf16(afr[0], bb, acc[0][bt], 0, 0, 0);
            acc[1][bt] = __builtin_amdgcn_mfma_f32_16x16x32_bf16(afr[1], bb, acc[1][bt], 0, 0, 0);
            acc[2][bt] = __builtin_amdgcn_mfma_f32_16x16x32_bf16(afr[2], bb, acc[2][bt], 0, 0, 0);
            acc[3][bt] = __builtin_amdgcn_mfma_f32_16x16x32_bf16(afr[3], bb, acc[3][bt], 0, 0, 0);
          }
        }
      }
    }
    if (kk < 4) y_finish(kk + 1);                      // writes other y buffer
    __syncthreads();   // drains stage DMA; y writes visible; frees kk bufs
  }

  __builtin_amdgcn_sched_barrier(0);   // keep epilogue loads out of K-loop region

  // ---- epilogue: z = acc + dist*w30 + b3 ; relu ; x W4 (256n -> 4)
  float b3v[4][4], w30v[4][4]; float4 w4v[4][4];
  #pragma unroll
  for (int at = 0; at < 4; ++at)
    #pragma unroll
    for (int r = 0; r < 4; ++r) {
      int n = (wn*4 + at)*16 + hi*4 + r;
      b3v[at][r]  = b3[n];
      w30v[at][r] = W3[n];                 // W3 row 0 = dist weights
      w4v[at][r]  = *reinterpret_cast<const float4*>(&W4[n*4]);
    }
  #pragma unroll
  for (int bt = 0; bt < 8; ++bt) {
    int pair = wp*128 + bt*16 + c15;
    float d = dist_lds[pair];
    float4 pe; pe.x=0.f; pe.y=0.f; pe.z=0.f; pe.w=0.f;
    #pragma unroll
    for (int at = 0; at < 4; ++at)
      #pragma unroll
      for (int r = 0; r < 4; ++r) {
        float z  = acc[at][bt][r] + d*w30v[at][r] + b3v[at][r];
        float rz = fmaxf(z, 0.f);
        pe.x += rz*w4v[at][r].x; pe.y += rz*w4v[at][r].y;
        pe.z += rz*w4v[at][r].z; pe.w += rz*w4v[at][r].w;
      }
    // reduce over hi (n-quarters): lanes differ only in hi for fixed c15
    pe.x += __shfl_xor(pe.x, 16); pe.y += __shfl_xor(pe.y, 16);
    pe.z += __shfl_xor(pe.z, 16); pe.w += __shfl_xor(pe.w, 16);
    pe.x += __shfl_xor(pe.x, 32); pe.y += __shfl_xor(pe.y, 32);
    pe.z += __shfl_xor(pe.z, 32); pe.w += __shfl_xor(pe.w, 32);
    if (hi == 0) *reinterpret_cast<float4*>(&u.partial[wn][pair][0]) = pe;
  }
  __syncthreads();
  if (tid < 256) {
    int pair = tid;
    float4 v;
    v.x = u.partial[0][pair][0] + u.partial[1][pair][0] + u.partial[2][pair][0] + u.partial[3][pair][0];
    v.y = u.partial[0][pair][1] + u.partial[1][pair][1] + u.partial[2][pair][1] + u.partial[3][pair][1];
    v.z = u.partial[0][pair][2] + u.partial[1][pair][2] + u.partial[2][pair][2] + u.partial[3][pair][2];
    v.w = u.partial[0][pair][3] + u.partial[1][pair][3] + u.partial[2][pair][3] + u.partial[3][pair][3];
    const float4 bv = *reinterpret_cast<const float4*>(b4);
    v.x += bv.x; v.y += bv.y; v.z += bv.z; v.w += bv.w;
    int il = it*16 + (pair >> 4);       // local i row
    int jl = jt*16 + (pair & 15);       // local j row
    *reinterpret_cast<float4*>(&out[(((size_t)b*256 + il)*256 + jl)*NE]) = v;
    if (it != jt)
      *reinterpret_cast<float4*>(&out[(((size_t)b*256 + jl)*256 + il)*NE]) = v;
  }
}

extern "C" void kernel_launch(void* const* d_in, const int* in_sizes, int n_in,
                              void* d_out, int out_size, void* d_ws, size_t ws_size,
                              hipStream_t stream) {
  const float* latent    = (const float*)d_in[0];
  const float* positions = (const float*)d_in[1];
  const float* atoms     = (const float*)d_in[2];
  const float* W1 = (const float*)d_in[3];
  const float* b1 = (const float*)d_in[4];
  const float* W2 = (const float*)d_in[5];
  const float* b2 = (const float*)d_in[6];
  const float* W3 = (const float*)d_in[7];
  const float* b3 = (const float*)d_in[8];
  const float* W4 = (const float*)d_in[9];
  const float* b4 = (const float*)d_in[10];
  float* out = (float*)d_out;

  char* ws = (char*)d_ws;
  float*  h_ws   = (float*)ws;                          // 8*256*256*4   = 2,097,152 B
  ushort* G_ws   = (ushort*)(ws + 2097152);             // 8*256*288*2   = 1,179,648 B
  ushort* W3T_ws = (ushort*)(ws + 2097152 + 1179648);   // 256*288*2     =   147,456 B

  hipLaunchKernelGGL(prep_h_kernel, dim3(256), dim3(256), 0, stream,
                     latent, atoms, W1, b1, W2, b2, h_ws, G_ws);
  hipLaunchKernelGGL(prep_w3t_kernel, dim3(256), dim3(256), 0, stream, W3, W3T_ws);
  hipLaunchKernelGGL(edge_main_kernel, dim3(1088), dim3(512), 0, stream,
                     positions, W3, b3, W4, b4, G_ws, W3T_ws, out);
}